// Round 6
// baseline (232.266 us; speedup 1.0000x reference)
//
#include <hip/hip_runtime.h>
#include <hip/hip_bf16.h>
#include <math.h>

// Problem constants: B=4, H=16, L=4096, D=64, S=128
constexpr int BB = 4;
constexpr int HH = 16;
constexpr int LL = 4096;
constexpr int DD = 64;
constexpr int SS = 128;
constexpr int BM = 64;     // rows per block

// R6: MFMA path with EXACT bf16x3 decomposition.
//   x = hi + mid + lo (bit-truncation planes; exact: 8+8+8 >= 24 mantissa bits)
//   x*c = hh + (hm+mh+mm+hl+lh+ml+lm) [+ ll ~2^-32, dropped]
// hi*hi accumulates in its own fp32 acc (64 adds, same class as numpy chain);
// the 7 small segments go to a second acc (|S|~2^-8, negligible noise);
// one final add. Products are EXACT (bf16*bf16 fits fp32) -> total error is
// fp32-reorder class (~1e-7), empirically safe per R2/R5 absmax=0.
// Fragments load straight from global fp32 (L1/L2-resident) -- no LDS tiles,
// no transpose, no LDS-instruction-rate wall (R5's limiter).
// Layouts (m89/m91-verified): A[m=lane&15][k=(lane>>4)*8+j] (b128 of 8 k);
// c is [code][d] = B^T form, same per-lane loader; D: row=(lane>>4)*4+reg,
// col=lane&15.

typedef __attribute__((ext_vector_type(8))) short bf16x8;
typedef __attribute__((ext_vector_type(4))) float f32x4;

__device__ __forceinline__ void split3(const float* __restrict__ p,
                                       bf16x8& H8, bf16x8& M8, bf16x8& L8) {
    float v[8];
    *(f32x4*)&v[0] = *(const f32x4*)p;
    *(f32x4*)&v[4] = *(const f32x4*)(p + 4);
    short H[8], M[8], L[8];
    #pragma unroll
    for (int e = 0; e < 8; ++e) {
        const float xv = v[e];
        const unsigned u0 = __float_as_uint(xv);
        const float hf = __uint_as_float(u0 & 0xFFFF0000u);
        const float r1 = xv - hf;                       // exact
        const unsigned u1 = __float_as_uint(r1);
        const float mf = __uint_as_float(u1 & 0xFFFF0000u);
        const float r2 = r1 - mf;                       // exact, <=8 sig bits
        const unsigned u2 = __float_as_uint(r2);
        H[e] = (short)(u0 >> 16);
        M[e] = (short)(u1 >> 16);
        L[e] = (short)(u2 >> 16);                       // exact bf16
    }
    H8 = *(bf16x8*)H; M8 = *(bf16x8*)M; L8 = *(bf16x8*)L;
}

__global__ __launch_bounds__(256, 2) void quantizer_kernel(
    const float* __restrict__ x,   // [B,H,L,D]
    const float* __restrict__ c,   // [H,S,D]
    float* __restrict__ out,       // [B,H,L,S] one-hot
    float* __restrict__ out_c)     // [H,S,D] copy of c
{
    const int tid = threadIdx.x;
    const int blk = blockIdx.x;
    const long long r0 = (long long)blk * BM;
    const int h = (int)((r0 >> 12) & (HH - 1));        // 64 | 4096
    const float* __restrict__ chead = c + (size_t)h * SS * DD;

    const int lane = tid & 63;
    const int wc = tid >> 6;       // wave 0..3 -> code strip [wc*32, wc*32+32)
    const int lm = lane & 15;      // m (x-row) / n (code) within 16x16 tile
    const int q  = lane >> 4;      // k-group: k = q*8 + j

    // acc[a][b]: a=0..3 row tiles (16 rows), b=0..1 code tiles (16 codes)
    f32x4 accB[4][2] = {};   // hi*hi
    f32x4 accS[4][2] = {};   // 7 small segments

    #pragma unroll
    for (int k0 = 0; k0 < DD; k0 += 32) {
        bf16x8 Ah[4], Am[4], Al[4], Bh[2], Bm[2], Bl[2];
        #pragma unroll
        for (int a = 0; a < 4; ++a) {
            const float* p = x + (size_t)(r0 + a * 16 + lm) * DD + k0 + q * 8;
            split3(p, Ah[a], Am[a], Al[a]);
        }
        #pragma unroll
        for (int b = 0; b < 2; ++b) {
            const float* p = chead + (size_t)(wc * 32 + b * 16 + lm) * DD + k0 + q * 8;
            split3(p, Bh[b], Bm[b], Bl[b]);
        }
        #pragma unroll
        for (int a = 0; a < 4; ++a) {
            #pragma unroll
            for (int b = 0; b < 2; ++b) {
                accB[a][b] = __builtin_amdgcn_mfma_f32_16x16x32_bf16(Ah[a], Bh[b], accB[a][b], 0, 0, 0);
                accS[a][b] = __builtin_amdgcn_mfma_f32_16x16x32_bf16(Ah[a], Bm[b], accS[a][b], 0, 0, 0);
                accS[a][b] = __builtin_amdgcn_mfma_f32_16x16x32_bf16(Am[a], Bh[b], accS[a][b], 0, 0, 0);
                accS[a][b] = __builtin_amdgcn_mfma_f32_16x16x32_bf16(Am[a], Bm[b], accS[a][b], 0, 0, 0);
                accS[a][b] = __builtin_amdgcn_mfma_f32_16x16x32_bf16(Ah[a], Bl[b], accS[a][b], 0, 0, 0);
                accS[a][b] = __builtin_amdgcn_mfma_f32_16x16x32_bf16(Al[a], Bh[b], accS[a][b], 0, 0, 0);
                accS[a][b] = __builtin_amdgcn_mfma_f32_16x16x32_bf16(Am[a], Bl[b], accS[a][b], 0, 0, 0);
                accS[a][b] = __builtin_amdgcn_mfma_f32_16x16x32_bf16(Al[a], Bm[b], accS[a][b], 0, 0, 0);
            }
        }
    }

    // ---- argmax epilogue via LDS candidate table ----
    __shared__ float rval[BM][65];   // +1 pad: conflict-free column scans
    __shared__ int   ridx[BM][65];
    __shared__ int   amax[BM];

    const int cg = wc * 16 + lm;     // candidate column 0..63
    #pragma unroll
    for (int a = 0; a < 4; ++a) {
        #pragma unroll
        for (int r = 0; r < 4; ++r) {
            const float v0 = accB[a][0][r] + accS[a][0][r];
            const float v1 = accB[a][1][r] + accS[a][1][r];
            const int c0 = wc * 32 + lm;
            const int c1 = wc * 32 + 16 + lm;
            const bool t = (v1 > v0);          // tie -> keep smaller index c0
            const int row = a * 16 + q * 4 + r;
            rval[row][cg] = t ? v1 : v0;
            ridx[row][cg] = t ? c1 : c0;
        }
    }
    __syncthreads();

    if (tid < BM) {
        float bv = rval[tid][0];
        int bc = ridx[tid][0];
        #pragma unroll 8
        for (int t = 1; t < 64; ++t) {
            const float v = rval[tid][t];
            const int ci = ridx[tid][t];
            if (v > bv || (v == bv && ci < bc)) { bv = v; bc = ci; }
        }
        amax[tid] = bc;
    }
    __syncthreads();

    // ---- cooperative coalesced one-hot write: 64 rows * 32 float4 ----
    float4* __restrict__ op = (float4*)(out + (size_t)r0 * SS);
    #pragma unroll
    for (int i = tid; i < BM * (SS / 4); i += 256) {
        const int rr = i >> 5;
        const int s0 = (i & 31) * 4;
        const int am = amax[rr];
        float4 v;
        v.x = (s0 + 0 == am) ? 1.f : 0.f;
        v.y = (s0 + 1 == am) ? 1.f : 0.f;
        v.z = (s0 + 2 == am) ? 1.f : 0.f;
        v.w = (s0 + 3 == am) ? 1.f : 0.f;
        op[i] = v;
    }

    // ---- copy c to second output (first 128 blocks x 256 thr = 32768 f4) ----
    if (blk < 128) {
        const float4* __restrict__ src = (const float4*)c;
        float4* __restrict__ dst = (float4*)out_c;
        const int idx = blk * 256 + tid;
        dst[idx] = src[idx];
    }
}

extern "C" void kernel_launch(void* const* d_in, const int* in_sizes, int n_in,
                              void* d_out, int out_size, void* d_ws, size_t ws_size,
                              hipStream_t stream) {
    const float* x = (const float*)d_in[0];   // [B,H,L,D] fp32
    const float* c = (const float*)d_in[1];   // [H,S,D]   fp32
    float* out = (float*)d_out;               // onehot [B,H,L,S] then c [H,S,D]
    float* out_c = out + (size_t)BB * HH * LL * SS;

    const int rows = BB * HH * LL;            // 262144
    const int blocks = rows / BM;             // 4096
    quantizer_kernel<<<blocks, 256, 0, stream>>>(x, c, out, out_c);
}

// Round 7
// 228.515 us; speedup vs baseline: 1.0164x; 1.0164x over previous
//
#include <hip/hip_runtime.h>
#include <hip/hip_bf16.h>
#include <math.h>

// Problem constants: B=4, H=16, L=4096, D=64, S=128
constexpr int BB = 4;
constexpr int HH = 16;
constexpr int LL = 4096;
constexpr int DD = 64;
constexpr int SS = 128;
constexpr int BM = 64;     // rows per block; grid 4096

// R7 = R6's exact bf16x3 MFMA numerics + R5's LDS-fed data path.
// Split fp32 -> 3 bf16 planes ONCE per block at staging; k-loop reads all
// MFMA fragments from LDS (issue-rate, no global-latency chains, no
// redundant per-wave split3). hi/mid planes: stride 72 shorts (144 B:
// 16B-aligned b128 reads, start bank 4*(lm+q)%32 -> uniform 8 acc/bank =
// minimal). lo planes: stride 64 (keeps total 79872 B < 81920 -> 2
// blocks/CU so HBM write phase overlaps the other block's compute).

typedef __attribute__((ext_vector_type(8))) short bf16x8;
typedef __attribute__((ext_vector_type(4))) float f32x4;

__device__ __forceinline__ void split3(const float* __restrict__ p,
                                       bf16x8& H8, bf16x8& M8, bf16x8& L8) {
    float v[8];
    *(f32x4*)&v[0] = *(const f32x4*)p;
    *(f32x4*)&v[4] = *(const f32x4*)(p + 4);
    short H[8], M[8], L[8];
    #pragma unroll
    for (int e = 0; e < 8; ++e) {
        const float xv = v[e];
        const unsigned u0 = __float_as_uint(xv);
        const float hf = __uint_as_float(u0 & 0xFFFF0000u);
        const float r1 = xv - hf;                       // exact
        const unsigned u1 = __float_as_uint(r1);
        const float mf = __uint_as_float(u1 & 0xFFFF0000u);
        const float r2 = r1 - mf;                       // exact, <=8 sig bits
        const unsigned u2 = __float_as_uint(r2);
        H[e] = (short)(u0 >> 16);
        M[e] = (short)(u1 >> 16);
        L[e] = (short)(u2 >> 16);                       // exact bf16
    }
    H8 = *(bf16x8*)H; M8 = *(bf16x8*)M; L8 = *(bf16x8*)L;
}

__global__ __launch_bounds__(256, 2) void quantizer_kernel(
    const float* __restrict__ x,   // [B,H,L,D]
    const float* __restrict__ c,   // [H,S,D]
    float* __restrict__ out,       // [B,H,L,S] one-hot
    float* __restrict__ out_c)     // [H,S,D] copy of c
{
    // 79872 B of planes; epilogue overlays the same region (33.5 KB used).
    alignas(16) __shared__ short smem[39936];
    short* __restrict__ sAh = smem;            // [64][72]
    short* __restrict__ sAm = smem + 4608;     // [64][72]
    short* __restrict__ sAl = smem + 9216;     // [64][64]
    short* __restrict__ sBh = smem + 13312;    // [128][72]
    short* __restrict__ sBm = smem + 22528;    // [128][72]
    short* __restrict__ sBl = smem + 31744;    // [128][64]

    const int tid = threadIdx.x;
    const int blk = blockIdx.x;
    const long long r0 = (long long)blk * BM;
    const int h = (int)((r0 >> 12) & (HH - 1));        // 64 | 4096
    const float* __restrict__ chead = c + (size_t)h * SS * DD;

    // ---- stage + split x: 512 octet-tasks (row, oct), 2 per thread ----
    #pragma unroll
    for (int i = 0; i < 2; ++i) {
        const int t = tid + i * 256;
        const int row = t >> 3, oct = t & 7;
        bf16x8 H, M, L;
        split3(x + (size_t)(r0 + row) * DD + oct * 8, H, M, L);
        *(bf16x8*)(sAh + row * 72 + oct * 8) = H;
        *(bf16x8*)(sAm + row * 72 + oct * 8) = M;
        *(bf16x8*)(sAl + row * 64 + oct * 8) = L;
    }
    // ---- stage + split c: 1024 octet-tasks (code, oct), 4 per thread ----
    #pragma unroll
    for (int i = 0; i < 4; ++i) {
        const int t = tid + i * 256;
        const int code = t >> 3, oct = t & 7;
        bf16x8 H, M, L;
        split3(chead + code * DD + oct * 8, H, M, L);
        *(bf16x8*)(sBh + code * 72 + oct * 8) = H;
        *(bf16x8*)(sBm + code * 72 + oct * 8) = M;
        *(bf16x8*)(sBl + code * 64 + oct * 8) = L;
    }
    __syncthreads();

    const int lane = tid & 63;
    const int wc = tid >> 6;       // wave -> code strip [wc*32, wc*32+32)
    const int lm = lane & 15;      // m (row) / n (code) within 16x16 tile
    const int q  = lane >> 4;      // k-group: k = q*8 + j

    f32x4 accB[4][2] = {};   // hi*hi
    f32x4 accS[4][2] = {};   // 7 small segments

    #pragma unroll
    for (int k0 = 0; k0 < DD; k0 += 32) {
        const int kk = k0 + q * 8;
        bf16x8 Ah[4], Am[4], Al[4], Bh[2], Bm[2], Bl[2];
        #pragma unroll
        for (int a = 0; a < 4; ++a) {
            const int m = a * 16 + lm;
            Ah[a] = *(const bf16x8*)(sAh + m * 72 + kk);
            Am[a] = *(const bf16x8*)(sAm + m * 72 + kk);
            Al[a] = *(const bf16x8*)(sAl + m * 64 + kk);
        }
        #pragma unroll
        for (int b = 0; b < 2; ++b) {
            const int n = wc * 32 + b * 16 + lm;
            Bh[b] = *(const bf16x8*)(sBh + n * 72 + kk);
            Bm[b] = *(const bf16x8*)(sBm + n * 72 + kk);
            Bl[b] = *(const bf16x8*)(sBl + n * 64 + kk);
        }
        #pragma unroll
        for (int a = 0; a < 4; ++a) {
            #pragma unroll
            for (int b = 0; b < 2; ++b) {
                accB[a][b] = __builtin_amdgcn_mfma_f32_16x16x32_bf16(Ah[a], Bh[b], accB[a][b], 0, 0, 0);
                accS[a][b] = __builtin_amdgcn_mfma_f32_16x16x32_bf16(Ah[a], Bm[b], accS[a][b], 0, 0, 0);
                accS[a][b] = __builtin_amdgcn_mfma_f32_16x16x32_bf16(Am[a], Bh[b], accS[a][b], 0, 0, 0);
                accS[a][b] = __builtin_amdgcn_mfma_f32_16x16x32_bf16(Am[a], Bm[b], accS[a][b], 0, 0, 0);
                accS[a][b] = __builtin_amdgcn_mfma_f32_16x16x32_bf16(Ah[a], Bl[b], accS[a][b], 0, 0, 0);
                accS[a][b] = __builtin_amdgcn_mfma_f32_16x16x32_bf16(Al[a], Bh[b], accS[a][b], 0, 0, 0);
                accS[a][b] = __builtin_amdgcn_mfma_f32_16x16x32_bf16(Am[a], Bl[b], accS[a][b], 0, 0, 0);
                accS[a][b] = __builtin_amdgcn_mfma_f32_16x16x32_bf16(Al[a], Bm[b], accS[a][b], 0, 0, 0);
            }
        }
    }

    __syncthreads();   // all plane reads done -> overlay epilogue tables
    float* __restrict__ rval = (float*)smem;            // [64][65]
    int*   __restrict__ ridx = (int*)smem + 4160;       // [64][65]
    int*   __restrict__ amax = ridx + 4160;             // [64]

    const int cg = wc * 16 + lm;     // candidate column 0..63
    #pragma unroll
    for (int a = 0; a < 4; ++a) {
        #pragma unroll
        for (int r = 0; r < 4; ++r) {
            const float v0 = accB[a][0][r] + accS[a][0][r];
            const float v1 = accB[a][1][r] + accS[a][1][r];
            const int c0 = wc * 32 + lm;
            const int c1 = wc * 32 + 16 + lm;
            const bool t = (v1 > v0);          // tie -> keep smaller index c0
            const int row = a * 16 + q * 4 + r;
            rval[row * 65 + cg] = t ? v1 : v0;
            ridx[row * 65 + cg] = t ? c1 : c0;
        }
    }
    __syncthreads();

    if (tid < BM) {
        float bv = rval[tid * 65];
        int bc = ridx[tid * 65];
        #pragma unroll 8
        for (int t = 1; t < 64; ++t) {
            const float v = rval[tid * 65 + t];
            const int ci = ridx[tid * 65 + t];
            if (v > bv || (v == bv && ci < bc)) { bv = v; bc = ci; }
        }
        amax[tid] = bc;
    }
    __syncthreads();

    // ---- cooperative coalesced one-hot write: 64 rows * 32 float4 ----
    float4* __restrict__ op = (float4*)(out + (size_t)r0 * SS);
    #pragma unroll
    for (int i = tid; i < BM * (SS / 4); i += 256) {
        const int rr = i >> 5;
        const int s0 = (i & 31) * 4;
        const int am = amax[rr];
        float4 v;
        v.x = (s0 + 0 == am) ? 1.f : 0.f;
        v.y = (s0 + 1 == am) ? 1.f : 0.f;
        v.z = (s0 + 2 == am) ? 1.f : 0.f;
        v.w = (s0 + 3 == am) ? 1.f : 0.f;
        op[i] = v;
    }

    // ---- copy c to second output (first 128 blocks x 256 thr) ----
    if (blk < 128) {
        const float4* __restrict__ src = (const float4*)c;
        float4* __restrict__ dst = (float4*)out_c;
        const int idx = blk * 256 + tid;
        dst[idx] = src[idx];
    }
}

extern "C" void kernel_launch(void* const* d_in, const int* in_sizes, int n_in,
                              void* d_out, int out_size, void* d_ws, size_t ws_size,
                              hipStream_t stream) {
    const float* x = (const float*)d_in[0];   // [B,H,L,D] fp32
    const float* c = (const float*)d_in[1];   // [H,S,D]   fp32
    float* out = (float*)d_out;               // onehot [B,H,L,S] then c [H,S,D]
    float* out_c = out + (size_t)BB * HH * LL * SS;

    const int rows = BB * HH * LL;            // 262144
    const int blocks = rows / BM;             // 4096
    quantizer_kernel<<<blocks, 256, 0, stream>>>(x, c, out, out_c);
}